// Round 13
// baseline (1214.805 us; speedup 1.0000x reference)
//
#include <hip/hip_runtime.h>
#include <hip/hip_bf16.h>

typedef __bf16 bf16x8 __attribute__((ext_vector_type(8)));
typedef float f32x4 __attribute__((ext_vector_type(4)));
typedef unsigned short ushort_t;

#define NPOS 512
#define CIN  5
#define CO   128

static __device__ __forceinline__ unsigned short f2bf(float f){
  union { __hip_bfloat16 h; unsigned short u; } cv;
  cv.h = __float2bfloat16(f);
  return cv.u;
}

// packed f32->bf16x2 (v_cvt_pk_bf16_f32 on gfx950) — RNE, 1 op per 2 values
static __device__ __forceinline__ unsigned cvtpk_u32(float a, float b){
  union { __hip_bfloat162 h2; unsigned u; } cv;
  cv.h2 = __float22bfloat162_rn(make_float2(a, b));
  return cv.u;
}

// packed u16 min/max (VOP3P) — one op handles two independent sort rows
static __device__ __forceinline__ unsigned pk_min_u16(unsigned a, unsigned b){
  unsigned d; asm("v_pk_min_u16 %0, %1, %2" : "=v"(d) : "v"(a), "v"(b)); return d;
}
static __device__ __forceinline__ unsigned pk_max_u16(unsigned a, unsigned b){
  unsigned d; asm("v_pk_max_u16 %0, %1, %2" : "=v"(d) : "v"(a), "v"(b)); return d;
}
// packed i16 max — relu on 2 packed bf16 (sign-correct; -0.0 -> +0.0)
static __device__ __forceinline__ unsigned pk_max_i16(unsigned a, unsigned b){
  unsigned d; asm("v_pk_max_i16 %0, %1, %2" : "=v"(d) : "v"(a), "v"(b)); return d;
}

// DPP cross-lane fetch (VALU pipe, no DS): 0xB1=xor1, 0x4E=xor2, 0x128=xor8
template<int CTRL>
static __device__ __forceinline__ unsigned mov_dpp_u32(unsigned v){
  return (unsigned)__builtin_amdgcn_mov_dpp((int)v, CTRL, 0xf, 0xf, true);
}
template<int CTRL>
static __device__ __forceinline__ float fadd_dpp(float s){
  union {float f; int i;} u; u.f = s;
  union {int i; float f;} q; q.i = __builtin_amdgcn_mov_dpp(u.i, CTRL, 0xf, 0xf, true);
  return s + q.f;
}

// ---------------- weight prep (+ pool weight table + counters) ----------------
// o = [w2b 65536 | w3b 65536 | w4b 32768 (PRE-SCALED by 1/512) | w1b 8192]
// Wt[c][i] (f32, 128x512) = pool weight at descending rank 511-i
// b4s[128] = b4/512 ; cnt[1024] = per-batch completion counters (zeroed HERE,
// every launch — d_ws is re-poisoned 0xAA before each timed call)
__global__ void k_prep(const float* __restrict__ w1, const float* __restrict__ w2,
                       const float* __restrict__ w3, const float* __restrict__ w4,
                       const float* __restrict__ pw, const float* __restrict__ b4,
                       ushort_t* __restrict__ o, float* __restrict__ Wt,
                       float* __restrict__ b4s, unsigned* __restrict__ cnt){
  int i = blockIdx.x*256 + threadIdx.x;
  if (i < 1024) cnt[i] = 0u;
  if (i < 65536)        o[i] = f2bf(w2[i]);
  else if (i < 131072)  o[i] = f2bf(w3[i-65536]);
  else if (i < 163840)  o[i] = f2bf(w4[i-131072] * (1.0f/512.0f));  // exp shift, exact
  else if (i < 172032){
    int j = i - 163840;
    int d = j >> 5, k = j & 31;
    o[i] = (k < CIN) ? f2bf(w1[d*CIN + k]) : (ushort_t)0;
  } else if (i < 237568){
    int j = i - 172032;
    int c = j >> 9, ii = j & 511;
    int rk = 511 - ii;
    float pos = (float)rk * (20.0f/511.0f);
    int idx = (int)pos; if (idx > 20) idx = 20;
    float frac = pos - (float)idx;
    int i2 = (idx+1 > 20) ? 20 : idx+1;
    float wl = pw[c*21 + idx], wr = pw[c*21 + i2];
    Wt[c*512 + ii] = wl + frac*(wr - wl);
  } else if (i < 237696){
    b4s[i-237568] = b4[i-237568] * (1.0f/512.0f);
  }
}

// ---------------- conv building blocks (R11 structure, no nt) ----------------
template<int NSD, int KSTR>
static __device__ __forceinline__ void preload_w(bf16x8 (&wr)[3][4],
    const ushort_t* __restrict__ Wb, int slot, int ks, int wave, int lane){
  const int m = lane & 15, quad = lane >> 4;
  const int d0 = wave * (NSD*16);
  #pragma unroll
  for (int sd=0; sd<NSD; sd++)
    wr[slot][sd] = *(const bf16x8*)(Wb + (d0 + sd*16 + m)*KSTR + ks*32 + quad*8);
}

// layers 1-3: W as A-operand, Act as B-operand. acc[nb][db]:
//   n = nb*16 + (lane&15), d = wave*64 + db*16 + quad*4 + rg
template<int NKS>
static __device__ __forceinline__ void mfma_WA(bf16x8 (&wr)[3][4],
    const ushort_t* __restrict__ Wb,
    const ushort_t* __restrict__ A0, const ushort_t* __restrict__ A1,
    const float* __restrict__ bias,
    f32x4 (&c0)[4][4], f32x4 (&c1)[4][4], int wave, int lane){
  const int quad = lane >> 4;
  f32x4 bvv[4];
  #pragma unroll
  for (int db=0; db<4; db++){
    float4 b4v = *(const float4*)(bias + wave*64 + db*16 + quad*4);
    bvv[db] = (f32x4){b4v.x, b4v.y, b4v.z, b4v.w};
  }
  #pragma unroll
  for (int ks=0; ks<NKS; ks++){
    if (ks+2 < NKS) preload_w<4,256>(wr, Wb, (ks+2)%3, ks+2, wave, lane);
    bf16x8 a0[4], a1[4];
    #pragma unroll
    for (int nb=0; nb<4; nb++){
      a0[nb] = *(const bf16x8*)(A0 + ((nb*512 + ks*64 + lane) << 3));
      a1[nb] = *(const bf16x8*)(A1 + ((nb*512 + ks*64 + lane) << 3));
    }
    #pragma unroll
    for (int db=0; db<4; db++){
      #pragma unroll
      for (int nb=0; nb<4; nb++){
        if (ks == 0){
          c0[nb][db] = __builtin_amdgcn_mfma_f32_16x16x32_bf16(wr[0][db], a0[nb], bvv[db], 0,0,0);
          c1[nb][db] = __builtin_amdgcn_mfma_f32_16x16x32_bf16(wr[0][db], a1[nb], bvv[db], 0,0,0);
        } else {
          c0[nb][db] = __builtin_amdgcn_mfma_f32_16x16x32_bf16(wr[ks%3][db], a0[nb], c0[nb][db], 0,0,0);
          c1[nb][db] = __builtin_amdgcn_mfma_f32_16x16x32_bf16(wr[ks%3][db], a1[nb], c1[nb][db], 0,0,0);
        }
      }
    }
  }
}

// layer 4: Act as A-operand. acc[sn][sd]: n = sn*16 + quad*4 + rg, d = wave*32 + sd*16 + m
static __device__ __forceinline__ void mfma_L4(bf16x8 (&wr)[3][4],
    const ushort_t* __restrict__ Wb,
    const ushort_t* __restrict__ A0, const ushort_t* __restrict__ A1,
    const float* __restrict__ bias,
    f32x4 (&c0)[4][4], f32x4 (&c1)[4][4], int wave, int lane){
  const int m = lane & 15;
  f32x4 bvv[2];
  #pragma unroll
  for (int sd=0; sd<2; sd++){
    float bv = bias[wave*32 + sd*16 + m];
    bvv[sd] = (f32x4){bv,bv,bv,bv};
  }
  #pragma unroll
  for (int ks=0; ks<8; ks++){
    if (ks+2 < 8) preload_w<2,256>(wr, Wb, (ks+2)%3, ks+2, wave, lane);
    bf16x8 a0[4], a1[4];
    #pragma unroll
    for (int sn=0; sn<4; sn++){
      a0[sn] = *(const bf16x8*)(A0 + ((sn*512 + ks*64 + lane) << 3));
      a1[sn] = *(const bf16x8*)(A1 + ((sn*512 + ks*64 + lane) << 3));
    }
    #pragma unroll
    for (int sd=0; sd<2; sd++){
      #pragma unroll
      for (int sn=0; sn<4; sn++){
        if (ks == 0){
          c0[sn][sd] = __builtin_amdgcn_mfma_f32_16x16x32_bf16(a0[sn], wr[0][sd], bvv[sd], 0,0,0);
          c1[sn][sd] = __builtin_amdgcn_mfma_f32_16x16x32_bf16(a1[sn], wr[0][sd], bvv[sd], 0,0,0);
        } else {
          c0[sn][sd] = __builtin_amdgcn_mfma_f32_16x16x32_bf16(a0[sn], wr[ks%3][sd], c0[sn][sd], 0,0,0);
          c1[sn][sd] = __builtin_amdgcn_mfma_f32_16x16x32_bf16(a1[sn], wr[ks%3][sd], c1[sn][sd], 0,0,0);
        }
      }
    }
  }
}

// layers 1-3 epilogue: +relu, ONE b64 write per acc tile (4 consecutive c)
static __device__ __forceinline__ void epilogue_relu(const f32x4 (&c)[4][4],
    ushort_t* __restrict__ dst, int wave, int lane){
  const int m = lane & 15, quad = lane >> 4;
  #pragma unroll
  for (int db=0; db<4; db++){
    int cb    = wave*64 + db*16 + quad*4;
    int colpt = (cb>>5)*64 + ((cb>>3)&3)*16;
    int half  = (quad & 1) ? 4 : 0;
    #pragma unroll
    for (int nb=0; nb<4; nb++){
      unsigned u01 = pk_max_i16(cvtpk_u32(c[nb][db][0], c[nb][db][1]), 0u);
      unsigned u23 = pk_max_i16(cvtpk_u32(c[nb][db][2], c[nb][db][3]), 0u);
      int chunk = nb*512 + colpt + m;
      *(uint2*)&dst[(chunk << 3) + half] = make_uint2(u01, u23);
    }
  }
}

// ---------------- packed 2-row bitonic sort + weighted pool ----------------
static __device__ __forceinline__ void ce_up(unsigned &a, unsigned &b){
  unsigned mn = pk_min_u16(a,b), mx = pk_max_u16(a,b); a = mn; b = mx;
}
static __device__ __forceinline__ void ce_dn(unsigned &a, unsigned &b){
  unsigned mn = pk_min_u16(a,b), mx = pk_max_u16(a,b); a = mx; b = mn;
}
static __device__ __forceinline__ void clean8(unsigned (&v)[8]){
  ce_up(v[0],v[4]); ce_up(v[1],v[5]); ce_up(v[2],v[6]); ce_up(v[3],v[7]);
  ce_up(v[0],v[2]); ce_up(v[1],v[3]); ce_up(v[4],v[6]); ce_up(v[5],v[7]);
  ce_up(v[0],v[1]); ce_up(v[2],v[3]); ce_up(v[4],v[5]); ce_up(v[6],v[7]);
}
static __device__ __forceinline__ void flip8(unsigned (&v)[8], unsigned f){
  #pragma unroll
  for (int i=0;i<8;i++) v[i] ^= f;
}
template<int CTRL>
static __device__ __forceinline__ void xr_dpp(unsigned (&v)[8], bool low){
  #pragma unroll
  for (int i=0;i<8;i++){
    unsigned p = mov_dpp_u32<CTRL>(v[i]);
    unsigned mn = pk_min_u16(v[i], p), mx = pk_max_u16(v[i], p);
    v[i] = low ? mn : mx;
  }
}
static __device__ __forceinline__ void xr_shfl(unsigned (&v)[8], int lm, bool low){
  #pragma unroll
  for (int i=0;i<8;i++){
    unsigned p = (unsigned)__shfl_xor((int)v[i], lm);
    unsigned mn = pk_min_u16(v[i], p), mx = pk_max_u16(v[i], p);
    v[i] = low ? mn : mx;
  }
}

// sorts rows (b,c0) and (b,c0+1), dot with Wt, writes out[b*129 + c0/+1]
static __device__ __forceinline__ void pool2(const ushort_t* __restrict__ rowp,
    const float* __restrict__ Wt, float* __restrict__ out, int b, int c0, int lane){
  uint4 ra = *(const uint4*)(rowp + lane*8);
  uint4 rb = *(const uint4*)(rowp + NPOS + lane*8);

  unsigned v[8];
  v[0] = (ra.x & 0xFFFFu) | (rb.x << 16);
  v[1] = (ra.x >> 16)     | (rb.x & 0xFFFF0000u);
  v[2] = (ra.y & 0xFFFFu) | (rb.y << 16);
  v[3] = (ra.y >> 16)     | (rb.y & 0xFFFF0000u);
  v[4] = (ra.z & 0xFFFFu) | (rb.z << 16);
  v[5] = (ra.z >> 16)     | (rb.z & 0xFFFF0000u);
  v[6] = (ra.w & 0xFFFFu) | (rb.w << 16);
  v[7] = (ra.w >> 16)     | (rb.w & 0xFFFF0000u);

  #pragma unroll
  for (int i=0;i<8;i++){
    unsigned sb = (v[i] >> 15) & 0x00010001u;
    v[i] = v[i] ^ 0x80008000u ^ (sb * 0x7FFFu);
  }

  const bool lo1  = (lane & 1)  == 0;
  const bool lo2  = (lane & 2)  == 0;
  const bool lo4  = (lane & 4)  == 0;
  const bool lo8  = (lane & 8)  == 0;
  const bool lo16 = (lane & 16) == 0;
  const bool lo32 = (lane & 32) == 0;

  const unsigned F8   = (lane & 1)  ? 0xFFFFFFFFu : 0u;
  const unsigned F16  = (lane & 2)  ? 0xFFFFFFFFu : 0u;
  const unsigned F32  = (lane & 4)  ? 0xFFFFFFFFu : 0u;
  const unsigned F64  = (lane & 8)  ? 0xFFFFFFFFu : 0u;
  const unsigned F128 = (lane & 16) ? 0xFFFFFFFFu : 0u;
  const unsigned F256 = (lane & 32) ? 0xFFFFFFFFu : 0u;

  ce_up(v[0],v[1]); ce_dn(v[2],v[3]); ce_up(v[4],v[5]); ce_dn(v[6],v[7]);
  ce_up(v[0],v[2]); ce_up(v[1],v[3]); ce_dn(v[4],v[6]); ce_dn(v[5],v[7]);
  ce_up(v[0],v[1]); ce_up(v[2],v[3]); ce_dn(v[4],v[5]); ce_dn(v[6],v[7]);

  flip8(v, F8);                                   // k=8
  clean8(v);
  flip8(v, F8 ^ F16);                             // k=16
  xr_dpp<0xB1>(v, lo1);
  clean8(v);
  flip8(v, F16 ^ F32);                            // k=32
  xr_dpp<0x4E>(v, lo2); xr_dpp<0xB1>(v, lo1);
  clean8(v);
  flip8(v, F32 ^ F64);                            // k=64
  xr_shfl(v, 4, lo4); xr_dpp<0x4E>(v, lo2); xr_dpp<0xB1>(v, lo1);
  clean8(v);
  flip8(v, F64 ^ F128);                           // k=128
  xr_dpp<0x128>(v, lo8); xr_shfl(v, 4, lo4); xr_dpp<0x4E>(v, lo2); xr_dpp<0xB1>(v, lo1);
  clean8(v);
  flip8(v, F128 ^ F256);                          // k=256
  xr_shfl(v, 16, lo16); xr_dpp<0x128>(v, lo8); xr_shfl(v, 4, lo4);
  xr_dpp<0x4E>(v, lo2); xr_dpp<0xB1>(v, lo1);
  clean8(v);
  flip8(v, F256);                                 // k=512
  xr_shfl(v, 32, lo32); xr_shfl(v, 16, lo16); xr_dpp<0x128>(v, lo8);
  xr_shfl(v, 4, lo4); xr_dpp<0x4E>(v, lo2); xr_dpp<0xB1>(v, lo1);
  clean8(v);

  #pragma unroll
  for (int i=0;i<8;i++){
    unsigned sb = ((~v[i]) >> 15) & 0x00010001u;
    v[i] = v[i] ^ 0x80008000u ^ (sb * 0x7FFFu);
  }

  float w0[8], w1a[8];
  *(float4*)&w0[0]  = *(const float4*)(Wt + c0*512 + lane*8);
  *(float4*)&w0[4]  = *(const float4*)(Wt + c0*512 + lane*8 + 4);
  *(float4*)&w1a[0] = *(const float4*)(Wt + (c0+1)*512 + lane*8);
  *(float4*)&w1a[4] = *(const float4*)(Wt + (c0+1)*512 + lane*8 + 4);

  float s0 = 0.f, s1 = 0.f;
  #pragma unroll
  for (int i=0;i<8;i++){
    union {unsigned u; float f;} lo, hi;
    lo.u = v[i] << 16;
    hi.u = v[i] & 0xFFFF0000u;
    s0 = fmaf(lo.f, w0[i],  s0);
    s1 = fmaf(hi.f, w1a[i], s1);
  }
  s0 = fadd_dpp<0xB1>(s0);  s1 = fadd_dpp<0xB1>(s1);
  s0 = fadd_dpp<0x4E>(s0);  s1 = fadd_dpp<0x4E>(s1);
  s0 = fadd_dpp<0x128>(s0); s1 = fadd_dpp<0x128>(s1);
  s0 += __shfl_xor(s0, 4);  s1 += __shfl_xor(s1, 4);
  s0 += __shfl_xor(s0, 16); s1 += __shfl_xor(s1, 16);
  s0 += __shfl_xor(s0, 32); s1 += __shfl_xor(s1, 32);

  if (lane == 0){
    out[b*129 + c0]     = s0;
    out[b*129 + c0 + 1] = s1;
  }
}

// ---------------- mega kernel: conv1..4 + last-block-done fused pool ----------------
__global__ __launch_bounds__(256,2) void k_mega(
  const float* __restrict__ x, const float* __restrict__ mask,
  const ushort_t* __restrict__ w1b, const float* __restrict__ b1,
  const ushort_t* __restrict__ w2b, const float* __restrict__ b2,
  const ushort_t* __restrict__ w3b, const float* __restrict__ b3,
  const ushort_t* __restrict__ w4b, const float* __restrict__ b4s,
  ushort_t* __restrict__ h4, unsigned* __restrict__ cnt,
  const float* __restrict__ Wt, float* __restrict__ out)
{
  __shared__ __align__(16) ushort_t Act0[64*256];   // 32 KB each, in-place
  __shared__ __align__(16) ushort_t Act1[64*256];
  __shared__ unsigned pflag;
  const int t    = threadIdx.x;
  const int bid  = blockIdx.x;
  const int b    = bid >> 2;
  const int n0   = (bid & 3) << 7;       // tiles at n0 and n0+64
  const int wave = t >> 6, lane = t & 63;

  bf16x8 wr[3][4];
  f32x4  c0[4][4], c1[4][4];

  // layer-1 fragments (ks=0 chunks) straight from global x, both tiles
  {
    const int sn = t >> 6, col = (t >> 4) & 3, n16 = t & 15;
    uint4 u0 = make_uint4(0u,0u,0u,0u), u1 = u0;
    if (col == 0){
      const float* xp = x + (size_t)b*CIN*NPOS + n0 + sn*16 + n16;
      u0.x = cvtpk_u32(xp[0],      xp[NPOS]);
      u0.y = cvtpk_u32(xp[2*NPOS], xp[3*NPOS]);
      u0.z = cvtpk_u32(xp[4*NPOS], 0.f);
      const float* xq = xp + 64;
      u1.x = cvtpk_u32(xq[0],      xq[NPOS]);
      u1.y = cvtpk_u32(xq[2*NPOS], xq[3*NPOS]);
      u1.z = cvtpk_u32(xq[4*NPOS], 0.f);
    }
    *(uint4*)&Act0[(sn*512 + col*16 + n16) << 3] = u0;
    *(uint4*)&Act1[(sn*512 + col*16 + n16) << 3] = u1;
  }
  preload_w<4,32>(wr, w1b, 0, 0, wave, lane);
  __syncthreads();                                // (1) x-frags ready

  mfma_WA<1>(wr, w1b, Act0, Act1, b1, c0, c1, wave, lane);   // layer 1
  __syncthreads();                                // (2)
  preload_w<4,256>(wr, w2b, 0, 0, wave, lane);
  preload_w<4,256>(wr, w2b, 1, 1, wave, lane);
  epilogue_relu(c0, Act0, wave, lane);
  epilogue_relu(c1, Act1, wave, lane);
  __syncthreads();                                // (3) Act = h1

  mfma_WA<8>(wr, w2b, Act0, Act1, b2, c0, c1, wave, lane);   // layer 2
  __syncthreads();                                // (4)
  preload_w<4,256>(wr, w3b, 0, 0, wave, lane);
  preload_w<4,256>(wr, w3b, 1, 1, wave, lane);
  epilogue_relu(c0, Act0, wave, lane);
  epilogue_relu(c1, Act1, wave, lane);
  __syncthreads();                                // (5) Act = h2

  mfma_WA<8>(wr, w3b, Act0, Act1, b3, c0, c1, wave, lane);   // layer 3
  __syncthreads();                                // (6)
  preload_w<2,256>(wr, w4b, 0, 0, wave, lane);
  preload_w<2,256>(wr, w4b, 1, 1, wave, lane);
  epilogue_relu(c0, Act0, wave, lane);
  epilogue_relu(c1, Act1, wave, lane);
  __syncthreads();                                // (7) Act = h3

  mfma_L4(wr, w4b, Act0, Act1, b4s, c0, c1, wave, lane);     // layer 4 (pre-scaled)
  {
    const int m = lane & 15, quad = lane >> 4;
    const float* mk = mask + (size_t)b*NPOS + n0;
    #pragma unroll
    for (int sd=0;sd<2;sd++){
      const int d = wave*32 + sd*16 + m;
      ushort_t* rowp = h4 + ((size_t)b*CO + d)*NPOS + n0;
      #pragma unroll
      for (int sn=0;sn<4;sn++){
        float4 mr0 = *(const float4*)(mk + sn*16 + quad*4);
        float4 mr1 = *(const float4*)(mk + 64 + sn*16 + quad*4);
        unsigned q0 = cvtpk_u32(c0[sn][sd][0] * mr0.x, c0[sn][sd][1] * mr0.y);
        unsigned q1 = cvtpk_u32(c0[sn][sd][2] * mr0.z, c0[sn][sd][3] * mr0.w);
        *(uint2*)(rowp + sn*16 + quad*4) = make_uint2(q0, q1);
        unsigned p0 = cvtpk_u32(c1[sn][sd][0] * mr1.x, c1[sn][sd][1] * mr1.y);
        unsigned p1 = cvtpk_u32(c1[sn][sd][2] * mr1.z, c1[sn][sd][3] * mr1.w);
        *(uint2*)(rowp + 64 + sn*16 + quad*4) = make_uint2(p0, p1);
      }
    }
  }

  // ---- last-block-done handoff (canonical threadfence reduction pattern) ----
  __threadfence();                                // release this block's h4 stores
  __syncthreads();
  if (t == 0)
    pflag = __hip_atomic_fetch_add(&cnt[b], 1u, __ATOMIC_ACQ_REL, __HIP_MEMORY_SCOPE_AGENT);
  __syncthreads();
  if (pflag != 3u) return;                        // not the 4th finisher

  // ---- pool phase: this block owns all 128 rows of batch b ----
  const ushort_t* hb = h4 + (size_t)b*CO*NPOS;
  #pragma unroll 1
  for (int iter=0; iter<16; iter++){
    int cc = iter*8 + wave*2;
    pool2(hb + (size_t)cc*NPOS, Wt, out, b, cc, lane);
  }

  // size feature
  if (wave == 0){
    float s = 0.f;
    #pragma unroll
    for (int i=0;i<2;i++){
      float4 mv = *(const float4*)(mask + (size_t)b*NPOS + lane*8 + i*4);
      s += mv.x + mv.y + mv.z + mv.w;
    }
    s = fadd_dpp<0xB1>(s); s = fadd_dpp<0x4E>(s); s = fadd_dpp<0x128>(s);
    s += __shfl_xor(s, 4); s += __shfl_xor(s, 16); s += __shfl_xor(s, 32);
    if (lane == 0) out[b*129 + 128] = s * (1.0f/128.0f);  // mean*4 = sum/512*4
  }
}

extern "C" void kernel_launch(void* const* d_in, const int* in_sizes, int n_in,
                              void* d_out, int out_size, void* d_ws, size_t ws_size,
                              hipStream_t stream){
  const float* x    = (const float*)d_in[0];
  const float* mask = (const float*)d_in[1];
  const float* w1   = (const float*)d_in[2];
  const float* b1   = (const float*)d_in[3];
  const float* w2   = (const float*)d_in[4];
  const float* b2   = (const float*)d_in[5];
  const float* w3   = (const float*)d_in[6];
  const float* b3   = (const float*)d_in[7];
  const float* w4   = (const float*)d_in[8];
  const float* b4   = (const float*)d_in[9];
  const float* pw   = (const float*)d_in[10];
  float* out = (float*)d_out;

  // ws: h4 (128MB) | w2b | w3b | w4b | w1b | Wt (f32 128x512) | b4s (128) | cnt (1024 u32)
  ushort_t* h4  = (ushort_t*)d_ws;
  ushort_t* w2b = h4 + (size_t)1024*CO*NPOS;
  ushort_t* w3b = w2b + 65536;
  ushort_t* w4b = w3b + 65536;
  ushort_t* w1b = w4b + 32768;
  float*    Wt  = (float*)(w1b + 8192);
  float*    b4s = Wt + 65536;
  unsigned* cnt = (unsigned*)(b4s + 128);

  k_prep <<<929,  256, 0, stream>>>(w1, w2, w3, w4, pw, b4, w2b, Wt, b4s, cnt);
  k_mega <<<4096, 256, 0, stream>>>(x, mask, w1b, b1, w2b, b2, w3b, b3, w4b, b4s,
                                    h4, cnt, Wt, out);
}

// Round 14
// 606.782 us; speedup vs baseline: 2.0020x; 2.0020x over previous
//
#include <hip/hip_runtime.h>
#include <hip/hip_bf16.h>

typedef __bf16 bf16x8 __attribute__((ext_vector_type(8)));
typedef float f32x4 __attribute__((ext_vector_type(4)));
typedef unsigned short ushort_t;

#define NPOS 512
#define CIN  5
#define CO   128

static __device__ __forceinline__ unsigned short f2bf(float f){
  union { __hip_bfloat16 h; unsigned short u; } cv;
  cv.h = __float2bfloat16(f);
  return cv.u;
}

// packed f32->bf16x2 (v_cvt_pk_bf16_f32 on gfx950) — RNE, 1 op per 2 values
static __device__ __forceinline__ unsigned cvtpk_u32(float a, float b){
  union { __hip_bfloat162 h2; unsigned u; } cv;
  cv.h2 = __float22bfloat162_rn(make_float2(a, b));
  return cv.u;
}

// packed u16 min/max (VOP3P) — one op handles two independent sort rows
static __device__ __forceinline__ unsigned pk_min_u16(unsigned a, unsigned b){
  unsigned d; asm("v_pk_min_u16 %0, %1, %2" : "=v"(d) : "v"(a), "v"(b)); return d;
}
static __device__ __forceinline__ unsigned pk_max_u16(unsigned a, unsigned b){
  unsigned d; asm("v_pk_max_u16 %0, %1, %2" : "=v"(d) : "v"(a), "v"(b)); return d;
}
// packed i16 max — relu on 2 packed bf16 (sign-correct; -0.0 -> +0.0)
static __device__ __forceinline__ unsigned pk_max_i16(unsigned a, unsigned b){
  unsigned d; asm("v_pk_max_i16 %0, %1, %2" : "=v"(d) : "v"(a), "v"(b)); return d;
}

// DPP cross-lane fetch (VALU pipe, no DS): 0xB1=xor1, 0x4E=xor2, 0x128=xor8
template<int CTRL>
static __device__ __forceinline__ unsigned mov_dpp_u32(unsigned v){
  return (unsigned)__builtin_amdgcn_mov_dpp((int)v, CTRL, 0xf, 0xf, true);
}
template<int CTRL>
static __device__ __forceinline__ float fadd_dpp(float s){
  union {float f; int i;} u; u.f = s;
  union {int i; float f;} q; q.i = __builtin_amdgcn_mov_dpp(u.i, CTRL, 0xf, 0xf, true);
  return s + q.f;
}

// ---------------- weight prep (+ pool weight table) ----------------
// o = [w2b 65536 | w3b 65536 | w4b 32768 (PRE-SCALED by 1/512) | w1b 8192]
// Wt[c][i] (f32, 128x512) = pool weight at descending rank 511-i ; b4s = b4/512
__global__ void k_prep(const float* __restrict__ w1, const float* __restrict__ w2,
                       const float* __restrict__ w3, const float* __restrict__ w4,
                       const float* __restrict__ pw, const float* __restrict__ b4,
                       ushort_t* __restrict__ o, float* __restrict__ Wt,
                       float* __restrict__ b4s){
  int i = blockIdx.x*256 + threadIdx.x;
  if (i < 65536)        o[i] = f2bf(w2[i]);
  else if (i < 131072)  o[i] = f2bf(w3[i-65536]);
  else if (i < 163840)  o[i] = f2bf(w4[i-131072] * (1.0f/512.0f));  // exp shift, exact
  else if (i < 172032){
    int j = i - 163840;
    int d = j >> 5, k = j & 31;
    o[i] = (k < CIN) ? f2bf(w1[d*CIN + k]) : (ushort_t)0;
  } else if (i < 237568){
    int j = i - 172032;
    int c = j >> 9, ii = j & 511;
    int rk = 511 - ii;
    float pos = (float)rk * (20.0f/511.0f);
    int idx = (int)pos; if (idx > 20) idx = 20;
    float frac = pos - (float)idx;
    int i2 = (idx+1 > 20) ? 20 : idx+1;
    float wl = pw[c*21 + idx], wr = pw[c*21 + i2];
    Wt[c*512 + ii] = wl + frac*(wr - wl);
  } else if (i < 237696){
    b4s[i-237568] = b4[i-237568] * (1.0f/512.0f);
  }
}

// ---------------- conv building blocks (R11 structure) ----------------
template<int NSD, int KSTR>
static __device__ __forceinline__ void preload_w(bf16x8 (&wr)[3][4],
    const ushort_t* __restrict__ Wb, int slot, int ks, int wave, int lane){
  const int m = lane & 15, quad = lane >> 4;
  const int d0 = wave * (NSD*16);
  #pragma unroll
  for (int sd=0; sd<NSD; sd++)
    wr[slot][sd] = *(const bf16x8*)(Wb + (d0 + sd*16 + m)*KSTR + ks*32 + quad*8);
}

// layers 1-3: W as A-operand, Act as B-operand. acc[nb][db]:
//   n = nb*16 + (lane&15), d = wave*64 + db*16 + quad*4 + rg
template<int NKS>
static __device__ __forceinline__ void mfma_WA(bf16x8 (&wr)[3][4],
    const ushort_t* __restrict__ Wb,
    const ushort_t* __restrict__ A0, const ushort_t* __restrict__ A1,
    const float* __restrict__ bias,
    f32x4 (&c0)[4][4], f32x4 (&c1)[4][4], int wave, int lane){
  const int quad = lane >> 4;
  f32x4 bvv[4];
  #pragma unroll
  for (int db=0; db<4; db++){
    float4 b4v = *(const float4*)(bias + wave*64 + db*16 + quad*4);
    bvv[db] = (f32x4){b4v.x, b4v.y, b4v.z, b4v.w};
  }
  #pragma unroll
  for (int ks=0; ks<NKS; ks++){
    if (ks+2 < NKS) preload_w<4,256>(wr, Wb, (ks+2)%3, ks+2, wave, lane);
    bf16x8 a0[4], a1[4];
    #pragma unroll
    for (int nb=0; nb<4; nb++){
      a0[nb] = *(const bf16x8*)(A0 + ((nb*512 + ks*64 + lane) << 3));
      a1[nb] = *(const bf16x8*)(A1 + ((nb*512 + ks*64 + lane) << 3));
    }
    #pragma unroll
    for (int db=0; db<4; db++){
      #pragma unroll
      for (int nb=0; nb<4; nb++){
        if (ks == 0){
          c0[nb][db] = __builtin_amdgcn_mfma_f32_16x16x32_bf16(wr[0][db], a0[nb], bvv[db], 0,0,0);
          c1[nb][db] = __builtin_amdgcn_mfma_f32_16x16x32_bf16(wr[0][db], a1[nb], bvv[db], 0,0,0);
        } else {
          c0[nb][db] = __builtin_amdgcn_mfma_f32_16x16x32_bf16(wr[ks%3][db], a0[nb], c0[nb][db], 0,0,0);
          c1[nb][db] = __builtin_amdgcn_mfma_f32_16x16x32_bf16(wr[ks%3][db], a1[nb], c1[nb][db], 0,0,0);
        }
      }
    }
  }
}

// layer 4: Act as A-operand. acc[sn][sd]: n = sn*16 + quad*4 + rg, d = wave*32 + sd*16 + m
static __device__ __forceinline__ void mfma_L4(bf16x8 (&wr)[3][4],
    const ushort_t* __restrict__ Wb,
    const ushort_t* __restrict__ A0, const ushort_t* __restrict__ A1,
    const float* __restrict__ bias,
    f32x4 (&c0)[4][4], f32x4 (&c1)[4][4], int wave, int lane){
  const int m = lane & 15;
  f32x4 bvv[2];
  #pragma unroll
  for (int sd=0; sd<2; sd++){
    float bv = bias[wave*32 + sd*16 + m];
    bvv[sd] = (f32x4){bv,bv,bv,bv};
  }
  #pragma unroll
  for (int ks=0; ks<8; ks++){
    if (ks+2 < 8) preload_w<2,256>(wr, Wb, (ks+2)%3, ks+2, wave, lane);
    bf16x8 a0[4], a1[4];
    #pragma unroll
    for (int sn=0; sn<4; sn++){
      a0[sn] = *(const bf16x8*)(A0 + ((sn*512 + ks*64 + lane) << 3));
      a1[sn] = *(const bf16x8*)(A1 + ((sn*512 + ks*64 + lane) << 3));
    }
    #pragma unroll
    for (int sd=0; sd<2; sd++){
      #pragma unroll
      for (int sn=0; sn<4; sn++){
        if (ks == 0){
          c0[sn][sd] = __builtin_amdgcn_mfma_f32_16x16x32_bf16(a0[sn], wr[0][sd], bvv[sd], 0,0,0);
          c1[sn][sd] = __builtin_amdgcn_mfma_f32_16x16x32_bf16(a1[sn], wr[0][sd], bvv[sd], 0,0,0);
        } else {
          c0[sn][sd] = __builtin_amdgcn_mfma_f32_16x16x32_bf16(a0[sn], wr[ks%3][sd], c0[sn][sd], 0,0,0);
          c1[sn][sd] = __builtin_amdgcn_mfma_f32_16x16x32_bf16(a1[sn], wr[ks%3][sd], c1[sn][sd], 0,0,0);
        }
      }
    }
  }
}

// layers 1-3 epilogue: +relu, ONE b64 write per acc tile (4 consecutive c)
static __device__ __forceinline__ void epilogue_relu(const f32x4 (&c)[4][4],
    ushort_t* __restrict__ dst, int wave, int lane){
  const int m = lane & 15, quad = lane >> 4;
  #pragma unroll
  for (int db=0; db<4; db++){
    int cb    = wave*64 + db*16 + quad*4;
    int colpt = (cb>>5)*64 + ((cb>>3)&3)*16;
    int half  = (quad & 1) ? 4 : 0;
    #pragma unroll
    for (int nb=0; nb<4; nb++){
      unsigned u01 = pk_max_i16(cvtpk_u32(c[nb][db][0], c[nb][db][1]), 0u);
      unsigned u23 = pk_max_i16(cvtpk_u32(c[nb][db][2], c[nb][db][3]), 0u);
      int chunk = nb*512 + colpt + m;
      *(uint2*)&dst[(chunk << 3) + half] = make_uint2(u01, u23);
    }
  }
}

// ---------------- packed 2-row bitonic sort + weighted pool ----------------
static __device__ __forceinline__ void ce_up(unsigned &a, unsigned &b){
  unsigned mn = pk_min_u16(a,b), mx = pk_max_u16(a,b); a = mn; b = mx;
}
static __device__ __forceinline__ void ce_dn(unsigned &a, unsigned &b){
  unsigned mn = pk_min_u16(a,b), mx = pk_max_u16(a,b); a = mx; b = mn;
}
static __device__ __forceinline__ void clean8(unsigned (&v)[8]){
  ce_up(v[0],v[4]); ce_up(v[1],v[5]); ce_up(v[2],v[6]); ce_up(v[3],v[7]);
  ce_up(v[0],v[2]); ce_up(v[1],v[3]); ce_up(v[4],v[6]); ce_up(v[5],v[7]);
  ce_up(v[0],v[1]); ce_up(v[2],v[3]); ce_up(v[4],v[5]); ce_up(v[6],v[7]);
}
static __device__ __forceinline__ void flip8(unsigned (&v)[8], unsigned f){
  #pragma unroll
  for (int i=0;i<8;i++) v[i] ^= f;
}
template<int CTRL>
static __device__ __forceinline__ void xr_dpp(unsigned (&v)[8], bool low){
  #pragma unroll
  for (int i=0;i<8;i++){
    unsigned p = mov_dpp_u32<CTRL>(v[i]);
    unsigned mn = pk_min_u16(v[i], p), mx = pk_max_u16(v[i], p);
    v[i] = low ? mn : mx;
  }
}
static __device__ __forceinline__ void xr_shfl(unsigned (&v)[8], int lm, bool low){
  #pragma unroll
  for (int i=0;i<8;i++){
    unsigned p = (unsigned)__shfl_xor((int)v[i], lm);
    unsigned mn = pk_min_u16(v[i], p), mx = pk_max_u16(v[i], p);
    v[i] = low ? mn : mx;
  }
}

// sorts rows (b,c0) and (b,c0+1), dot with Wt, writes out[b*129 + c0/+1]
static __device__ __forceinline__ void pool2(const ushort_t* __restrict__ rowp,
    const float* __restrict__ Wt, float* __restrict__ out, int b, int c0, int lane){
  uint4 ra = *(const uint4*)(rowp + lane*8);
  uint4 rb = *(const uint4*)(rowp + NPOS + lane*8);

  unsigned v[8];
  v[0] = (ra.x & 0xFFFFu) | (rb.x << 16);
  v[1] = (ra.x >> 16)     | (rb.x & 0xFFFF0000u);
  v[2] = (ra.y & 0xFFFFu) | (rb.y << 16);
  v[3] = (ra.y >> 16)     | (rb.y & 0xFFFF0000u);
  v[4] = (ra.z & 0xFFFFu) | (rb.z << 16);
  v[5] = (ra.z >> 16)     | (rb.z & 0xFFFF0000u);
  v[6] = (ra.w & 0xFFFFu) | (rb.w << 16);
  v[7] = (ra.w >> 16)     | (rb.w & 0xFFFF0000u);

  #pragma unroll
  for (int i=0;i<8;i++){
    unsigned sb = (v[i] >> 15) & 0x00010001u;
    v[i] = v[i] ^ 0x80008000u ^ (sb * 0x7FFFu);
  }

  const bool lo1  = (lane & 1)  == 0;
  const bool lo2  = (lane & 2)  == 0;
  const bool lo4  = (lane & 4)  == 0;
  const bool lo8  = (lane & 8)  == 0;
  const bool lo16 = (lane & 16) == 0;
  const bool lo32 = (lane & 32) == 0;

  const unsigned F8   = (lane & 1)  ? 0xFFFFFFFFu : 0u;
  const unsigned F16  = (lane & 2)  ? 0xFFFFFFFFu : 0u;
  const unsigned F32  = (lane & 4)  ? 0xFFFFFFFFu : 0u;
  const unsigned F64  = (lane & 8)  ? 0xFFFFFFFFu : 0u;
  const unsigned F128 = (lane & 16) ? 0xFFFFFFFFu : 0u;
  const unsigned F256 = (lane & 32) ? 0xFFFFFFFFu : 0u;

  ce_up(v[0],v[1]); ce_dn(v[2],v[3]); ce_up(v[4],v[5]); ce_dn(v[6],v[7]);
  ce_up(v[0],v[2]); ce_up(v[1],v[3]); ce_dn(v[4],v[6]); ce_dn(v[5],v[7]);
  ce_up(v[0],v[1]); ce_up(v[2],v[3]); ce_dn(v[4],v[5]); ce_dn(v[6],v[7]);

  flip8(v, F8);                                   // k=8
  clean8(v);
  flip8(v, F8 ^ F16);                             // k=16
  xr_dpp<0xB1>(v, lo1);
  clean8(v);
  flip8(v, F16 ^ F32);                            // k=32
  xr_dpp<0x4E>(v, lo2); xr_dpp<0xB1>(v, lo1);
  clean8(v);
  flip8(v, F32 ^ F64);                            // k=64
  xr_shfl(v, 4, lo4); xr_dpp<0x4E>(v, lo2); xr_dpp<0xB1>(v, lo1);
  clean8(v);
  flip8(v, F64 ^ F128);                           // k=128
  xr_dpp<0x128>(v, lo8); xr_shfl(v, 4, lo4); xr_dpp<0x4E>(v, lo2); xr_dpp<0xB1>(v, lo1);
  clean8(v);
  flip8(v, F128 ^ F256);                          // k=256
  xr_shfl(v, 16, lo16); xr_dpp<0x128>(v, lo8); xr_shfl(v, 4, lo4);
  xr_dpp<0x4E>(v, lo2); xr_dpp<0xB1>(v, lo1);
  clean8(v);
  flip8(v, F256);                                 // k=512
  xr_shfl(v, 32, lo32); xr_shfl(v, 16, lo16); xr_dpp<0x128>(v, lo8);
  xr_shfl(v, 4, lo4); xr_dpp<0x4E>(v, lo2); xr_dpp<0xB1>(v, lo1);
  clean8(v);

  #pragma unroll
  for (int i=0;i<8;i++){
    unsigned sb = ((~v[i]) >> 15) & 0x00010001u;
    v[i] = v[i] ^ 0x80008000u ^ (sb * 0x7FFFu);
  }

  float w0[8], w1a[8];
  *(float4*)&w0[0]  = *(const float4*)(Wt + c0*512 + lane*8);
  *(float4*)&w0[4]  = *(const float4*)(Wt + c0*512 + lane*8 + 4);
  *(float4*)&w1a[0] = *(const float4*)(Wt + (c0+1)*512 + lane*8);
  *(float4*)&w1a[4] = *(const float4*)(Wt + (c0+1)*512 + lane*8 + 4);

  float s0 = 0.f, s1 = 0.f;
  #pragma unroll
  for (int i=0;i<8;i++){
    union {unsigned u; float f;} lo, hi;
    lo.u = v[i] << 16;
    hi.u = v[i] & 0xFFFF0000u;
    s0 = fmaf(lo.f, w0[i],  s0);
    s1 = fmaf(hi.f, w1a[i], s1);
  }
  s0 = fadd_dpp<0xB1>(s0);  s1 = fadd_dpp<0xB1>(s1);
  s0 = fadd_dpp<0x4E>(s0);  s1 = fadd_dpp<0x4E>(s1);
  s0 = fadd_dpp<0x128>(s0); s1 = fadd_dpp<0x128>(s1);
  s0 += __shfl_xor(s0, 4);  s1 += __shfl_xor(s1, 4);
  s0 += __shfl_xor(s0, 16); s1 += __shfl_xor(s1, 16);
  s0 += __shfl_xor(s0, 32); s1 += __shfl_xor(s1, 32);

  if (lane == 0){
    out[b*129 + c0]     = s0;
    out[b*129 + c0 + 1] = s1;
  }
}

// ---------------- mega kernel: block owns batch b — conv x4 tiles, then pool ----
// No cross-block handoff -> no fences, no atomics (R13's __threadfence caused
// L2 writebacks that evicted W and 5x'd the kernel). All h4[b] rows are written
// by THIS block; __syncthreads() + same-CU L1/L2 gives visibility for free.
__global__ __launch_bounds__(256,2) void k_mega(
  const float* __restrict__ x, const float* __restrict__ mask,
  const ushort_t* __restrict__ w1b, const float* __restrict__ b1,
  const ushort_t* __restrict__ w2b, const float* __restrict__ b2,
  const ushort_t* __restrict__ w3b, const float* __restrict__ b3,
  const ushort_t* __restrict__ w4b, const float* __restrict__ b4s,
  ushort_t* __restrict__ h4, const float* __restrict__ Wt,
  float* __restrict__ out)
{
  __shared__ __align__(16) ushort_t Act0[64*256];   // 32 KB each, in-place
  __shared__ __align__(16) ushort_t Act1[64*256];
  const int t    = threadIdx.x;
  const int b    = blockIdx.x;
  const int wave = t >> 6, lane = t & 63;

  bf16x8 wr[3][4];
  f32x4  c0[4][4], c1[4][4];

  #pragma unroll 1
  for (int np = 0; np < 4; np++){
    const int n0 = np << 7;              // tiles at n0 and n0+64

    // layer-1 fragments (ks=0 chunks) straight from global x, both tiles
    {
      const int sn = t >> 6, col = (t >> 4) & 3, n16 = t & 15;
      uint4 u0 = make_uint4(0u,0u,0u,0u), u1 = u0;
      if (col == 0){
        const float* xp = x + (size_t)b*CIN*NPOS + n0 + sn*16 + n16;
        u0.x = cvtpk_u32(xp[0],      xp[NPOS]);
        u0.y = cvtpk_u32(xp[2*NPOS], xp[3*NPOS]);
        u0.z = cvtpk_u32(xp[4*NPOS], 0.f);
        const float* xq = xp + 64;
        u1.x = cvtpk_u32(xq[0],      xq[NPOS]);
        u1.y = cvtpk_u32(xq[2*NPOS], xq[3*NPOS]);
        u1.z = cvtpk_u32(xq[4*NPOS], 0.f);
      }
      *(uint4*)&Act0[(sn*512 + col*16 + n16) << 3] = u0;
      *(uint4*)&Act1[(sn*512 + col*16 + n16) << 3] = u1;
    }
    preload_w<4,32>(wr, w1b, 0, 0, wave, lane);
    __syncthreads();                              // (1) x-frags ready

    mfma_WA<1>(wr, w1b, Act0, Act1, b1, c0, c1, wave, lane);   // layer 1
    __syncthreads();                              // (2)
    preload_w<4,256>(wr, w2b, 0, 0, wave, lane);
    preload_w<4,256>(wr, w2b, 1, 1, wave, lane);
    epilogue_relu(c0, Act0, wave, lane);
    epilogue_relu(c1, Act1, wave, lane);
    __syncthreads();                              // (3) Act = h1

    mfma_WA<8>(wr, w2b, Act0, Act1, b2, c0, c1, wave, lane);   // layer 2
    __syncthreads();                              // (4)
    preload_w<4,256>(wr, w3b, 0, 0, wave, lane);
    preload_w<4,256>(wr, w3b, 1, 1, wave, lane);
    epilogue_relu(c0, Act0, wave, lane);
    epilogue_relu(c1, Act1, wave, lane);
    __syncthreads();                              // (5) Act = h2

    mfma_WA<8>(wr, w3b, Act0, Act1, b3, c0, c1, wave, lane);   // layer 3
    __syncthreads();                              // (6)
    preload_w<2,256>(wr, w4b, 0, 0, wave, lane);
    preload_w<2,256>(wr, w4b, 1, 1, wave, lane);
    epilogue_relu(c0, Act0, wave, lane);
    epilogue_relu(c1, Act1, wave, lane);
    __syncthreads();                              // (7) Act = h3

    mfma_L4(wr, w4b, Act0, Act1, b4s, c0, c1, wave, lane);     // layer 4
    {
      const int m = lane & 15, quad = lane >> 4;
      const float* mk = mask + (size_t)b*NPOS + n0;
      #pragma unroll
      for (int sd=0;sd<2;sd++){
        const int d = wave*32 + sd*16 + m;
        ushort_t* rowp = h4 + ((size_t)b*CO + d)*NPOS + n0;
        #pragma unroll
        for (int sn=0;sn<4;sn++){
          float4 mr0 = *(const float4*)(mk + sn*16 + quad*4);
          float4 mr1 = *(const float4*)(mk + 64 + sn*16 + quad*4);
          unsigned q0 = cvtpk_u32(c0[sn][sd][0] * mr0.x, c0[sn][sd][1] * mr0.y);
          unsigned q1 = cvtpk_u32(c0[sn][sd][2] * mr0.z, c0[sn][sd][3] * mr0.w);
          *(uint2*)(rowp + sn*16 + quad*4) = make_uint2(q0, q1);
          unsigned p0 = cvtpk_u32(c1[sn][sd][0] * mr1.x, c1[sn][sd][1] * mr1.y);
          unsigned p1 = cvtpk_u32(c1[sn][sd][2] * mr1.z, c1[sn][sd][3] * mr1.w);
          *(uint2*)(rowp + 64 + sn*16 + quad*4) = make_uint2(p0, p1);
        }
      }
    }
    __syncthreads();                              // (8) Act reuse + h4 drain
  }

  // ---- pool phase: all 128 rows of batch b were written by THIS block ----
  const ushort_t* hb = h4 + (size_t)b*CO*NPOS;
  #pragma unroll 1
  for (int iter=0; iter<16; iter++){
    int cc = iter*8 + wave*2;
    pool2(hb + (size_t)cc*NPOS, Wt, out, b, cc, lane);
  }

  // size feature
  if (wave == 0){
    float s = 0.f;
    #pragma unroll
    for (int i=0;i<2;i++){
      float4 mv = *(const float4*)(mask + (size_t)b*NPOS + lane*8 + i*4);
      s += mv.x + mv.y + mv.z + mv.w;
    }
    s = fadd_dpp<0xB1>(s); s = fadd_dpp<0x4E>(s); s = fadd_dpp<0x128>(s);
    s += __shfl_xor(s, 4); s += __shfl_xor(s, 16); s += __shfl_xor(s, 32);
    if (lane == 0) out[b*129 + 128] = s * (1.0f/128.0f);  // mean*4 = sum/512*4
  }
}

extern "C" void kernel_launch(void* const* d_in, const int* in_sizes, int n_in,
                              void* d_out, int out_size, void* d_ws, size_t ws_size,
                              hipStream_t stream){
  const float* x    = (const float*)d_in[0];
  const float* mask = (const float*)d_in[1];
  const float* w1   = (const float*)d_in[2];
  const float* b1   = (const float*)d_in[3];
  const float* w2   = (const float*)d_in[4];
  const float* b2   = (const float*)d_in[5];
  const float* w3   = (const float*)d_in[6];
  const float* b3   = (const float*)d_in[7];
  const float* w4   = (const float*)d_in[8];
  const float* b4   = (const float*)d_in[9];
  const float* pw   = (const float*)d_in[10];
  float* out = (float*)d_out;

  // ws: h4 (128MB) | w2b | w3b | w4b | w1b | Wt (f32 128x512) | b4s (128)
  ushort_t* h4  = (ushort_t*)d_ws;
  ushort_t* w2b = h4 + (size_t)1024*CO*NPOS;
  ushort_t* w3b = w2b + 65536;
  ushort_t* w4b = w3b + 65536;
  ushort_t* w1b = w4b + 32768;
  float*    Wt  = (float*)(w1b + 8192);
  float*    b4s = Wt + 65536;

  k_prep <<<929,  256, 0, stream>>>(w1, w2, w3, w4, pw, b4, w2b, Wt, b4s);
  k_mega <<<1024, 256, 0, stream>>>(x, mask, w1b, b1, w2b, b2, w3b, b3, w4b, b4s,
                                    h4, Wt, out);
}